// Round 7
// baseline (464.448 us; speedup 1.0000x reference)
//
#include <hip/hip_runtime.h>
#include <math.h>

#define HDIM 768
#define NG   192        // HDIM/4 float4 groups
#define LMAX 512

__device__ __forceinline__ float dot4(const float4 a, const float4 b) {
  return a.x * b.x + a.y * b.y + a.z * b.z + a.w * b.w;
}
__device__ __forceinline__ void fma4(float4& a, const float s, const float4 b) {
  a.x += s * b.x; a.y += s * b.y; a.z += s * b.z; a.w += s * b.w;
}
__device__ __forceinline__ void scale4(float4& a, const float s) {
  a.x *= s; a.y *= s; a.z *= s; a.w *= s;
}

// ---------------- kernel 0: input-width detection (slot writes) ----------------
__global__ __launch_bounds__(256) void detect_slots(const unsigned* __restrict__ mask_w,
                                                    const unsigned* __restrict__ smap_w,
                                                    unsigned* __restrict__ slots,
                                                    int mask_words, int smap_words) {
  __shared__ unsigned red[2];
  const int b = blockIdx.x, tid = threadIdx.x;
  if (tid < 2) red[tid] = 0;
  __syncthreads();
  const int gtid = b * 256 + tid, gsz = gridDim.x * 256;
  unsigned acc = 0;
  for (int i = gtid; i < mask_words / 2; i += gsz) acc |= mask_w[2 * i + 1];
  unsigned acc2 = 0;
  for (int i = gtid; i < smap_words / 2; i += gsz) acc2 |= smap_w[2 * i + 1];
  if (acc)  atomicOr(&red[0], 1u);
  if (acc2) atomicOr(&red[1], 1u);
  __syncthreads();
  if (tid == 0) { slots[b] = red[0]; slots[64 + b] = red[1]; }
}

// ---------------- kernel 1: Wc = Wq^T * Wk, c0 = bq * Wk (proven r6 version) ----------
__global__ __launch_bounds__(256) void prep_wc(const float* __restrict__ Wq,
                                               const float* __restrict__ Wk,
                                               const float* __restrict__ bq,
                                               float* __restrict__ Wc,
                                               float* __restrict__ c0, int H) {
  __shared__ float As[16][33];
  __shared__ float Bs[16][65];
  __shared__ float bqs[16];
  const int i0 = blockIdx.x * 32, j0 = blockIdx.y * 64;
  const int idx = threadIdx.x;
  const int li = idx & 31, lk = idx >> 5;
  const int lj = idx & 63, lk2 = idx >> 6;
  const int tc = idx & 15, tr = idx >> 4;
  float c[2][4] = {{0.f,0.f,0.f,0.f},{0.f,0.f,0.f,0.f}};
  float cb[4] = {0.f,0.f,0.f,0.f};
  const bool bias_lane = (blockIdx.x == 0) && (tr == 0);
  for (int o0 = 0; o0 < H; o0 += 16) {
    __syncthreads();
    As[lk][li]       = Wq[(size_t)(o0 + lk) * H + i0 + li];
    As[lk + 8][li]   = Wq[(size_t)(o0 + lk + 8) * H + i0 + li];
    Bs[lk2][lj]      = Wk[(size_t)(o0 + lk2) * H + j0 + lj];
    Bs[lk2 + 4][lj]  = Wk[(size_t)(o0 + lk2 + 4) * H + j0 + lj];
    Bs[lk2 + 8][lj]  = Wk[(size_t)(o0 + lk2 + 8) * H + j0 + lj];
    Bs[lk2 + 12][lj] = Wk[(size_t)(o0 + lk2 + 12) * H + j0 + lj];
    if (idx < 16) bqs[idx] = bq[o0 + idx];
    __syncthreads();
#pragma unroll
    for (int k = 0; k < 16; ++k) {
      const float a0 = As[k][tr * 2], a1 = As[k][tr * 2 + 1];
      const float b0 = Bs[k][tc * 4],     b1 = Bs[k][tc * 4 + 1];
      const float b2 = Bs[k][tc * 4 + 2], b3 = Bs[k][tc * 4 + 3];
      c[0][0] += a0 * b0; c[0][1] += a0 * b1; c[0][2] += a0 * b2; c[0][3] += a0 * b3;
      c[1][0] += a1 * b0; c[1][1] += a1 * b1; c[1][2] += a1 * b2; c[1][3] += a1 * b3;
      if (bias_lane) {
        const float bv = bqs[k];
        cb[0] += bv * b0; cb[1] += bv * b1; cb[2] += bv * b2; cb[3] += bv * b3;
      }
    }
  }
#pragma unroll
  for (int j = 0; j < 4; ++j) {
    Wc[(size_t)(i0 + tr * 2) * H + j0 + tc * 4 + j]     = c[0][j];
    Wc[(size_t)(i0 + tr * 2 + 1) * H + j0 + tc * 4 + j] = c[1][j];
  }
  if (bias_lane) {
#pragma unroll
    for (int j = 0; j < 4; ++j) c0[j0 + tc * 4 + j] = cb[j];
  }
}

// ---------------- kernel 2: partial sums over L-halves ----------------
// block (n, half): sums rows [half*L/2, half*L/2+L/2). Writes UNDIVIDED partial.
__global__ __launch_bounds__(384) void mean2(const float* __restrict__ hs,
                                             float* __restrict__ part, int L) {
  __shared__ float4 red2[NG];
  const int n = blockIdx.x >> 1, half = blockIdx.x & 1;
  const int tid = threadIdx.x;
  const int sub = tid / NG, t = tid - sub * NG;
  const int Lh = L / 2, r0 = half * Lh;
  const float4* hb = reinterpret_cast<const float4*>(hs) + ((size_t)n * L + r0) * NG;
  float ax = 0.f, ay = 0.f, az = 0.f, aw = 0.f;
  int l = sub;
  for (; l + 16 <= Lh; l += 16) {
    float4 u[8];
#pragma unroll
    for (int i = 0; i < 8; ++i) u[i] = hb[(size_t)(l + 2 * i) * NG + t];
#pragma unroll
    for (int i = 0; i < 8; ++i) { ax += u[i].x; ay += u[i].y; az += u[i].z; aw += u[i].w; }
  }
  for (; l < Lh; l += 2) {
    float4 u = hb[(size_t)l * NG + t];
    ax += u.x; ay += u.y; az += u.z; aw += u.w;
  }
  if (sub == 1) { float4 o; o.x = ax; o.y = ay; o.z = az; o.w = aw; red2[t] = o; }
  __syncthreads();
  if (sub == 0) {
    const float4 r = red2[t];
    float4 o; o.x = ax + r.x; o.y = ay + r.y; o.z = az + r.z; o.w = aw + r.w;
    reinterpret_cast<float4*>(part + (size_t)(n * 2 + half) * HDIM)[t] = o;
  }
}

// ---------------- kernel 3: V = (P0+P1)/L * Wc + c0 ----------------
__global__ __launch_bounds__(256) void gemmV(const float* __restrict__ P,
                                             const float* __restrict__ Wc,
                                             const float* __restrict__ c0,
                                             float* __restrict__ V,
                                             int M, int Nn, int K, float invL) {
  __shared__ float As[32][17];
  __shared__ float Bs[16][65];
  const int m0 = blockIdx.x * 32, n0 = blockIdx.y * 64;
  const int idx = threadIdx.x;
  const int lc = idx & 15, lr = idx >> 4;
  const int bc = idx & 63, br = idx >> 6;
  const int tc = idx & 15, tr = idx >> 4;
  float c[2][4] = {{0.f,0.f,0.f,0.f},{0.f,0.f,0.f,0.f}};
  for (int k0 = 0; k0 < K; k0 += 16) {
    __syncthreads();
    {
      const int m1 = m0 + lr, m2 = m0 + lr + 16;
      As[lr][lc]      = (P[(size_t)(2 * m1) * K + k0 + lc] + P[(size_t)(2 * m1 + 1) * K + k0 + lc]) * invL;
      As[lr + 16][lc] = (P[(size_t)(2 * m2) * K + k0 + lc] + P[(size_t)(2 * m2 + 1) * K + k0 + lc]) * invL;
    }
    Bs[br][bc]      = Wc[(size_t)(k0 + br) * Nn + n0 + bc];
    Bs[br + 4][bc]  = Wc[(size_t)(k0 + br + 4) * Nn + n0 + bc];
    Bs[br + 8][bc]  = Wc[(size_t)(k0 + br + 8) * Nn + n0 + bc];
    Bs[br + 12][bc] = Wc[(size_t)(k0 + br + 12) * Nn + n0 + bc];
    __syncthreads();
#pragma unroll
    for (int k = 0; k < 16; ++k) {
      const float a0 = As[tr * 2][k], a1 = As[tr * 2 + 1][k];
      const float b0 = Bs[k][tc * 4], b1 = Bs[k][tc * 4 + 1];
      const float b2 = Bs[k][tc * 4 + 2], b3 = Bs[k][tc * 4 + 3];
      c[0][0] += a0 * b0; c[0][1] += a0 * b1; c[0][2] += a0 * b2; c[0][3] += a0 * b3;
      c[1][0] += a1 * b0; c[1][1] += a1 * b1; c[1][2] += a1 * b2; c[1][3] += a1 * b3;
    }
  }
#pragma unroll
  for (int j = 0; j < 4; ++j) {
    const float bv = c0[n0 + tc * 4 + j];
    V[(size_t)(m0 + tr * 2) * Nn + n0 + tc * 4 + j]     = c[0][j] + bv;
    V[(size_t)(m0 + tr * 2 + 1) * Nn + n0 + tc * 4 + j] = c[1][j] + bv;
  }
}

// ---------------- kernel 4: pool (scores + wave-local online softmax + weighted sum) --
// block (n, half), 256 thr. Wave w owns rows r ≡ (3-w) mod 4 of its half,
// processed DESCENDING (starts in the L3-resident tail of mean2's stream).
// 2-row register double-buffer, no barriers in the main loop.
__global__ __launch_bounds__(256) void pool(const float* __restrict__ hs,
                                            const unsigned* __restrict__ mask_w,
                                            const float* __restrict__ V,
                                            const unsigned* __restrict__ slots,
                                            float* __restrict__ acc_out,
                                            float* __restrict__ ms_out, int L) {
  __shared__ int   mrow[256];
  __shared__ float4 redv[4][NG];   // 12 KB
  __shared__ float mw[4], sw[4];
  __shared__ unsigned mfl;
  const int bid = blockIdx.x;
  const int n = bid >> 1, half = bid & 1;
  const int tid = threadIdx.x, w = tid >> 6, lane = tid & 63;
  const int Lh = L / 2, r0 = half * Lh;

  if (tid == 0) mfl = 0u;
  __syncthreads();
  if (tid < 64 && slots[tid]) atomicOr(&mfl, 1u);
  __syncthreads();
  const int mask_is_i32 = (mfl != 0);
  {
    const size_t idx = (size_t)n * L + r0 + tid;
    mrow[tid] = (int)(mask_is_i32 ? mask_w[idx] : mask_w[2 * idx]);
  }
  __syncthreads();

  const float4* v4 = reinterpret_cast<const float4*>(V + (size_t)n * HDIM);
  const float4 vf0 = v4[lane], vf1 = v4[64 + lane], vf2 = v4[128 + lane];
  const float4* hb = reinterpret_cast<const float4*>(hs) + ((size_t)n * L + r0) * NG;
  const float scale = 1.0f / sqrtf((float)HDIM);

  float m = -3.0e38f, ss = 0.f;
  float4 A0 = {0,0,0,0}, A1 = {0,0,0,0}, A2 = {0,0,0,0};
  float4 xa[2][3], xb[2][3];

  auto ld = [&](float4 (&X)[2][3], int b) {
#pragma unroll
    for (int u = 0; u < 2; ++u) {
      const int rr = Lh - 1 - 4 * (2 * b + u) - w;   // descending
      const float4* rp = hb + (size_t)rr * NG;
      X[u][0] = rp[lane]; X[u][1] = rp[64 + lane]; X[u][2] = rp[128 + lane];
    }
  };
  auto pr = [&](float4 (&X)[2][3], int b) {
    float s[2];
#pragma unroll
    for (int u = 0; u < 2; ++u) {
      const int rr = Lh - 1 - 4 * (2 * b + u) - w;
      float p = dot4(X[u][0], vf0) + dot4(X[u][1], vf1) + dot4(X[u][2], vf2);
#pragma unroll
      for (int off = 32; off > 0; off >>= 1) p += __shfl_xor(p, off, 64);
      s[u] = (mrow[rr] == 0) ? -1e9f : p * scale;
    }
    const float mc = fmaxf(s[0], s[1]);
    if (mc > m) {   // defer-rescale (wave-uniform)
      const float f = __expf(m - mc);
      ss *= f; scale4(A0, f); scale4(A1, f); scale4(A2, f);
      m = mc;
    }
#pragma unroll
    for (int u = 0; u < 2; ++u) {
      const float pq = __expf(s[u] - m);
      ss += pq;
      fma4(A0, pq, X[u][0]); fma4(A1, pq, X[u][1]); fma4(A2, pq, X[u][2]);
    }
  };

  ld(xa, 0);
  const int nb = Lh / 8;   // 32 batches of 2 rows per wave
  for (int b = 0; b < nb; b += 2) {
    ld(xb, b + 1);
    pr(xa, b);
    if (b + 2 < nb) ld(xa, b + 2);
    pr(xb, b + 1);
  }

  // ---- 4-way split-softmax merge (one barrier), write block partial ----
  if (lane == 0) { mw[w] = m; sw[w] = ss; }
  redv[w][lane]       = A0;
  redv[w][64 + lane]  = A1;
  redv[w][128 + lane] = A2;
  __syncthreads();
  const float M = fmaxf(fmaxf(mw[0], mw[1]), fmaxf(mw[2], mw[3]));
  const float f0 = __expf(mw[0] - M), f1 = __expf(mw[1] - M);
  const float f2 = __expf(mw[2] - M), f3 = __expf(mw[3] - M);
  const float S = sw[0] * f0 + sw[1] * f1 + sw[2] * f2 + sw[3] * f3;
  const float* redp = (const float*)redv;
  const int pidx = n * 2 + half;
#pragma unroll
  for (int part = 0; part < 3; ++part) {
    const int col = part * 256 + tid;
    acc_out[(size_t)pidx * HDIM + col] =
        redp[col] * f0 + redp[HDIM + col] * f1 + redp[2 * HDIM + col] * f2 + redp[3 * HDIM + col] * f3;
  }
  if (tid == 0) { ms_out[pidx * 2] = M; ms_out[pidx * 2 + 1] = S; }
}

// ---------------- kernel 5: merge halves + segment mean (proven r5 version) --------
__global__ __launch_bounds__(256) void merge_segmean(const float* __restrict__ acc,
                                                     const float* __restrict__ ms,
                                                     const void* __restrict__ smap,
                                                     const unsigned* __restrict__ slots_s,
                                                     float* __restrict__ out, int N) {
  __shared__ unsigned fsh;
  const int t = blockIdx.x, tid = threadIdx.x;
  const int col = blockIdx.y * 256 + tid;
  if (tid == 0) {
    unsigned f = 0;
    for (int i = 0; i < 64; ++i) f |= slots_s[i];
    fsh = f;
  }
  __syncthreads();
  const int smap_is_i32 = (fsh != 0);
  float a = 0.f;
  int cnt = 0;
  for (int i = 0; i < N; ++i) {
    const int s = smap_is_i32 ? ((const int*)smap)[i]
                              : (int)((const long long*)smap)[i];
    if (s != t) continue;
    const float m0 = ms[(i * 2) * 2],     q0 = ms[(i * 2) * 2 + 1];
    const float m1 = ms[(i * 2 + 1) * 2], q1 = ms[(i * 2 + 1) * 2 + 1];
    const float M = fmaxf(m0, m1);
    const float f0 = __expf(m0 - M), f1 = __expf(m1 - M);
    const float S = q0 * f0 + q1 * f1;
    const float o = (acc[(size_t)(i * 2) * HDIM + col] * f0 +
                     acc[(size_t)(i * 2 + 1) * HDIM + col] * f1) / S;
    a += o; ++cnt;
  }
  out[(size_t)t * HDIM + col] = a / (float)(cnt > 0 ? cnt : 1);
}

extern "C" void kernel_launch(void* const* d_in, const int* in_sizes, int n_in,
                              void* d_out, int out_size, void* d_ws, size_t ws_size,
                              hipStream_t stream) {
  const float*    hs     = (const float*)d_in[0];
  const unsigned* mask_w = (const unsigned*)d_in[1];
  const void*     smap   = d_in[2];
  const float*    Wq     = (const float*)d_in[3];
  const float*    bq     = (const float*)d_in[4];
  const float*    Wk     = (const float*)d_in[5];
  // d_in[6] = bk: dead (adds per-row constant to scores -> softmax-invariant)

  const int N = in_sizes[2];           // 512
  const int L = in_sizes[1] / N;       // 512
  const int H = in_sizes[4];           // 768 (== HDIM)
  const int T = out_size / H;          // 32
  const size_t NH = (size_t)N * H;

  float* Wc   = (float*)d_ws;                  // [H,H]
  float* c0   = Wc + (size_t)H * H;            // [H]
  float* part = c0 + H;                        // [2N,H]
  float* V    = part + 2 * NH;                 // [N,H]
  float* acc  = V + NH;                        // [2N,H]
  float* ms   = acc + 2 * NH;                  // [2N,2]
  unsigned* slots = (unsigned*)(ms + 4 * N);   // [128]
  (void)ws_size; (void)n_in;

  detect_slots<<<64, 256, 0, stream>>>(mask_w, (const unsigned*)smap, slots, N * L, N);
  prep_wc<<<dim3(H / 32, H / 64), 256, 0, stream>>>(Wq, Wk, bq, Wc, c0, H);
  mean2<<<2 * N, 384, 0, stream>>>(hs, part, L);
  gemmV<<<dim3(N / 32, H / 64), 256, 0, stream>>>(part, Wc, c0, V, N, H, H, 1.0f / (float)L);
  pool<<<2 * N, 256, 0, stream>>>(hs, mask_w, V, slots, acc, ms, L);
  merge_segmean<<<dim3(T, 3), 256, 0, stream>>>(acc, ms, smap, slots + 64, (float*)d_out, N);
}

// Round 8
// 446.104 us; speedup vs baseline: 1.0411x; 1.0411x over previous
//
#include <hip/hip_runtime.h>
#include <math.h>

#define HDIM 768
#define NG   192        // HDIM/4 float4 groups
#define LMAX 512

__device__ __forceinline__ float dot4(const float4 a, const float4 b) {
  return a.x * b.x + a.y * b.y + a.z * b.z + a.w * b.w;
}
__device__ __forceinline__ void fma4(float4& a, const float s, const float4 b) {
  a.x += s * b.x; a.y += s * b.y; a.z += s * b.z; a.w += s * b.w;
}
__device__ __forceinline__ void scale4(float4& a, const float s) {
  a.x *= s; a.y *= s; a.z *= s; a.w *= s;
}

// ---------------- kernel 0: input-width detection (slot writes) ----------------
__global__ __launch_bounds__(256) void detect_slots(const unsigned* __restrict__ mask_w,
                                                    const unsigned* __restrict__ smap_w,
                                                    unsigned* __restrict__ slots,
                                                    int mask_words, int smap_words) {
  __shared__ unsigned red[2];
  const int b = blockIdx.x, tid = threadIdx.x;
  if (tid < 2) red[tid] = 0;
  __syncthreads();
  const int gtid = b * 256 + tid, gsz = gridDim.x * 256;
  unsigned acc = 0;
  for (int i = gtid; i < mask_words / 2; i += gsz) acc |= mask_w[2 * i + 1];
  unsigned acc2 = 0;
  for (int i = gtid; i < smap_words / 2; i += gsz) acc2 |= smap_w[2 * i + 1];
  if (acc)  atomicOr(&red[0], 1u);
  if (acc2) atomicOr(&red[1], 1u);
  __syncthreads();
  if (tid == 0) { slots[b] = red[0]; slots[64 + b] = red[1]; }
}

// ---------------- kernel 1: Wc = Wq^T * Wk, c0 = bq * Wk ----------------
__global__ __launch_bounds__(256) void prep_wc(const float* __restrict__ Wq,
                                               const float* __restrict__ Wk,
                                               const float* __restrict__ bq,
                                               float* __restrict__ Wc,
                                               float* __restrict__ c0, int H) {
  __shared__ float As[16][33];
  __shared__ float Bs[16][65];
  __shared__ float bqs[16];
  const int i0 = blockIdx.x * 32, j0 = blockIdx.y * 64;
  const int idx = threadIdx.x;
  const int li = idx & 31, lk = idx >> 5;
  const int lj = idx & 63, lk2 = idx >> 6;
  const int tc = idx & 15, tr = idx >> 4;
  float c[2][4] = {{0.f,0.f,0.f,0.f},{0.f,0.f,0.f,0.f}};
  float cb[4] = {0.f,0.f,0.f,0.f};
  const bool bias_lane = (blockIdx.x == 0) && (tr == 0);
  for (int o0 = 0; o0 < H; o0 += 16) {
    __syncthreads();
    As[lk][li]       = Wq[(size_t)(o0 + lk) * H + i0 + li];
    As[lk + 8][li]   = Wq[(size_t)(o0 + lk + 8) * H + i0 + li];
    Bs[lk2][lj]      = Wk[(size_t)(o0 + lk2) * H + j0 + lj];
    Bs[lk2 + 4][lj]  = Wk[(size_t)(o0 + lk2 + 4) * H + j0 + lj];
    Bs[lk2 + 8][lj]  = Wk[(size_t)(o0 + lk2 + 8) * H + j0 + lj];
    Bs[lk2 + 12][lj] = Wk[(size_t)(o0 + lk2 + 12) * H + j0 + lj];
    if (idx < 16) bqs[idx] = bq[o0 + idx];
    __syncthreads();
#pragma unroll
    for (int k = 0; k < 16; ++k) {
      const float a0 = As[k][tr * 2], a1 = As[k][tr * 2 + 1];
      const float b0 = Bs[k][tc * 4],     b1 = Bs[k][tc * 4 + 1];
      const float b2 = Bs[k][tc * 4 + 2], b3 = Bs[k][tc * 4 + 3];
      c[0][0] += a0 * b0; c[0][1] += a0 * b1; c[0][2] += a0 * b2; c[0][3] += a0 * b3;
      c[1][0] += a1 * b0; c[1][1] += a1 * b1; c[1][2] += a1 * b2; c[1][3] += a1 * b3;
      if (bias_lane) {
        const float bv = bqs[k];
        cb[0] += bv * b0; cb[1] += bv * b1; cb[2] += bv * b2; cb[3] += bv * b3;
      }
    }
  }
#pragma unroll
  for (int j = 0; j < 4; ++j) {
    Wc[(size_t)(i0 + tr * 2) * H + j0 + tc * 4 + j]     = c[0][j];
    Wc[(size_t)(i0 + tr * 2 + 1) * H + j0 + tc * 4 + j] = c[1][j];
  }
  if (bias_lane) {
#pragma unroll
    for (int j = 0; j < 4; ++j) c0[j0 + tc * 4 + j] = cb[j];
  }
}

// ---------------- kernel 2: fused mean -> GEMV -> scores/softmax/pool ----------------
// One block per n, 384 threads. Pass 1: forward mean. GEMV from L2-resident Wc.
// Pass 2: descending interleaved rows; wave-local online softmax; 3-buffer
// modulo-scheduled pipeline with score/acc decoupled (score of batch j+1
// overlaps acc of batch j; loads issued 3 batches ahead).
__global__ __launch_bounds__(384, 3) void fused(const float* __restrict__ hs,
                                                const unsigned* __restrict__ mask_w,
                                                const float* __restrict__ Wc,
                                                const float* __restrict__ c0,
                                                const unsigned* __restrict__ slots,
                                                float* __restrict__ pooled, int L) {
  __shared__ float4 red2[NG];
  __shared__ float4 meanv4[NG];
  __shared__ float4 vv4[NG];
  __shared__ float4 redv4[6][NG];
  __shared__ float mw[6], sw[6];
  __shared__ int   mrow[LMAX];
  __shared__ unsigned mfl;
  const int n = blockIdx.x, tid = threadIdx.x;
  const int w = tid >> 6, lane = tid & 63;

  if (tid == 0) mfl = 0u;
  __syncthreads();
  if (tid < 64 && slots[tid]) atomicOr(&mfl, 1u);

  // ---- pass 1: mean over L (forward stream) ----
  const int half = tid / NG, t = tid - half * NG;
  const float4* hb = reinterpret_cast<const float4*>(hs) + (size_t)n * L * NG;
  float ax = 0.f, ay = 0.f, az = 0.f, aw = 0.f;
  int l = half;
  for (; l + 16 <= L; l += 16) {
    float4 u[8];
#pragma unroll
    for (int i = 0; i < 8; ++i) u[i] = hb[(size_t)(l + 2 * i) * NG + t];
#pragma unroll
    for (int i = 0; i < 8; ++i) { ax += u[i].x; ay += u[i].y; az += u[i].z; aw += u[i].w; }
  }
  for (; l < L; l += 2) {
    float4 u = hb[(size_t)l * NG + t];
    ax += u.x; ay += u.y; az += u.z; aw += u.w;
  }
  if (half == 1) { float4 o; o.x = ax; o.y = ay; o.z = az; o.w = aw; red2[t] = o; }
  __syncthreads();

  if (half == 0) {
    const float inv = 1.0f / (float)L;
    const float4 r = red2[t];
    float4 o;
    o.x = (ax + r.x) * inv; o.y = (ay + r.y) * inv;
    o.z = (az + r.z) * inv; o.w = (aw + r.w) * inv;
    meanv4[t] = o;
  }
  const int mask_is_i32 = (mfl != 0);
  for (int tt = tid; tt < L; tt += 384) {
    const size_t idx = (size_t)n * L + tt;
    mrow[tt] = (int)(mask_is_i32 ? mask_w[idx] : mask_w[2 * idx]);
  }
  __syncthreads();

  // ---- GEMV: v = mean * Wc + c0 ----
  {
    const int c1 = tid, c2 = tid + 384;
    float acc1 = 0.f, acc2 = 0.f;
    const float* wp = Wc;
    for (int o = 0; o < HDIM; o += 4) {
      const float4 mv = meanv4[o >> 2];
      acc1 += mv.x * wp[c1] + mv.y * wp[HDIM + c1] + mv.z * wp[2 * HDIM + c1] + mv.w * wp[3 * HDIM + c1];
      acc2 += mv.x * wp[c2] + mv.y * wp[HDIM + c2] + mv.z * wp[2 * HDIM + c2] + mv.w * wp[3 * HDIM + c2];
      wp += 4 * HDIM;
    }
    ((float*)vv4)[c1] = acc1 + c0[c1];
    ((float*)vv4)[c2] = acc2 + c0[c2];
  }
  __syncthreads();

  // ---- pass 2: 3-buffer modulo-scheduled pipeline ----
  const float4 vf0 = vv4[lane], vf1 = vv4[64 + lane], vf2 = vv4[128 + lane];
  const float scale = 1.0f / sqrtf((float)HDIM);
  const int cnt = (L - 1 - w) / 6 + 1;      // row-slots this wave owns (85/86)
  float m = -3.0e38f, ss = 0.f;
  float4 A0 = {0,0,0,0}, A1 = {0,0,0,0}, A2 = {0,0,0,0};
  float4 xa[2][3], xb[2][3], xc[2][3];

  // batch b covers row-slots 2b, 2b+1; slot jj -> row L-1-6*jj-w (descending)
  auto ld = [&](float4 (&X)[2][3], int b) {
#pragma unroll
    for (int u = 0; u < 2; ++u) {
      const int jj = 2 * b + u;
      const int rr = (jj < cnt) ? (L - 1 - 6 * jj - w) : 0;
      const float4* rp = hb + (size_t)rr * NG;
      X[u][0] = rp[lane]; X[u][1] = rp[64 + lane]; X[u][2] = rp[128 + lane];
    }
  };
  // pure score phase: dot + wave reduce + mask (no softmax-state dependence)
  auto score = [&](float4 (&X)[2][3], int b, float (&s)[2]) {
#pragma unroll
    for (int u = 0; u < 2; ++u) {
      const int jj = 2 * b + u;
      const int r = L - 1 - 6 * jj - w;
      float p = dot4(X[u][0], vf0) + dot4(X[u][1], vf1) + dot4(X[u][2], vf2);
#pragma unroll
      for (int off = 32; off > 0; off >>= 1) p += __shfl_xor(p, off, 64);
      s[u] = (jj >= cnt || mrow[r & (LMAX - 1)] == 0) ? -1e9f : p * scale;
    }
  };
  // softmax-state update + accumulate
  auto acc = [&](float4 (&X)[2][3], int b, const float (&s)[2]) {
    const float mc = fmaxf(s[0], s[1]);
    if (mc > m) {   // defer-rescale (wave-uniform)
      const float f = __expf(m - mc);
      ss *= f; scale4(A0, f); scale4(A1, f); scale4(A2, f);
      m = mc;
    }
#pragma unroll
    for (int u = 0; u < 2; ++u) {
      const float pq = (2 * b + u < cnt) ? __expf(s[u] - m) : 0.f;
      ss += pq;
      fma4(A0, pq, X[u][0]); fma4(A1, pq, X[u][1]); fma4(A2, pq, X[u][2]);
    }
  };

  float sa[2], sb[2], sc2[2];
  ld(xa, 0); ld(xb, 1); ld(xc, 2);
  score(xa, 0, sa);
  // 45 batches (90 row-slots >= max cnt 86): 15 iterations x 3
  for (int b = 0; b < 45; b += 3) {
    score(xb, b + 1, sb);  acc(xa, b, sa);      if (b + 3 < 45) ld(xa, b + 3);
    score(xc, b + 2, sc2); acc(xb, b + 1, sb);  if (b + 4 < 45) ld(xb, b + 4);
    score(xa, b + 3, sa);  acc(xc, b + 2, sc2); if (b + 5 < 45) ld(xc, b + 5);
  }

  // ---- 6-way split-softmax merge ----
  if (lane == 0) { mw[w] = m; sw[w] = ss; }
  redv4[w][lane]       = A0;
  redv4[w][64 + lane]  = A1;
  redv4[w][128 + lane] = A2;
  __syncthreads();
  float M = mw[0];
#pragma unroll
  for (int j = 1; j < 6; ++j) M = fmaxf(M, mw[j]);
  float f[6], S = 0.f;
#pragma unroll
  for (int j = 0; j < 6; ++j) { f[j] = __expf(mw[j] - M); S += sw[j] * f[j]; }
  const float invS = 1.0f / S;
  const float* redp = (const float*)redv4;
#pragma unroll
  for (int part = 0; part < 2; ++part) {
    const int col = part * 384 + tid;
    float o = 0.f;
#pragma unroll
    for (int j = 0; j < 6; ++j) o += redp[j * HDIM + col] * f[j];
    pooled[(size_t)n * HDIM + col] = o * invS;
  }
}

// ---------------- kernel 3: segment mean ----------------
__global__ __launch_bounds__(256) void segmean(const float* __restrict__ pooled,
                                               const void* __restrict__ smap,
                                               const unsigned* __restrict__ slots_s,
                                               float* __restrict__ out, int N) {
  __shared__ unsigned fsh;
  const int t = blockIdx.x, tid = threadIdx.x;
  const int col = blockIdx.y * 256 + tid;
  if (tid == 0) {
    unsigned f = 0;
    for (int i = 0; i < 64; ++i) f |= slots_s[i];
    fsh = f;
  }
  __syncthreads();
  const int smap_is_i32 = (fsh != 0);
  float a = 0.f;
  int cnt = 0;
  for (int i = 0; i < N; ++i) {
    const int s = smap_is_i32 ? ((const int*)smap)[i]
                              : (int)((const long long*)smap)[i];
    if (s == t) { a += pooled[(size_t)i * HDIM + col]; ++cnt; }
  }
  out[(size_t)t * HDIM + col] = a / (float)(cnt > 0 ? cnt : 1);
}

extern "C" void kernel_launch(void* const* d_in, const int* in_sizes, int n_in,
                              void* d_out, int out_size, void* d_ws, size_t ws_size,
                              hipStream_t stream) {
  const float*    hs     = (const float*)d_in[0];
  const unsigned* mask_w = (const unsigned*)d_in[1];
  const void*     smap   = d_in[2];
  const float*    Wq     = (const float*)d_in[3];
  const float*    bq     = (const float*)d_in[4];
  const float*    Wk     = (const float*)d_in[5];
  // d_in[6] = bk: dead (adds per-row constant to scores -> softmax-invariant)

  const int N = in_sizes[2];           // 512
  const int L = in_sizes[1] / N;       // 512
  const int H = in_sizes[4];           // 768 (== HDIM)
  const int T = out_size / H;          // 32

  float* Wc     = (float*)d_ws;                    // [H,H]
  float* c0     = Wc + (size_t)H * H;              // [H]
  float* pooled = c0 + H;                          // [N,H]
  unsigned* slots = (unsigned*)(pooled + (size_t)N * H);  // [128]
  (void)ws_size; (void)n_in;

  detect_slots<<<64, 256, 0, stream>>>(mask_w, (const unsigned*)smap, slots, N * L, N);
  prep_wc<<<dim3(H / 32, H / 64), 256, 0, stream>>>(Wq, Wk, bq, Wc, c0, H);
  fused<<<N, 384, 0, stream>>>(hs, mask_w, Wc, c0, slots, pooled, L);
  segmean<<<dim3(T, 3), 256, 0, stream>>>(pooled, smap, slots + 64, (float*)d_out, N);
}

// Round 9
// 433.492 us; speedup vs baseline: 1.0714x; 1.0291x over previous
//
#include <hip/hip_runtime.h>
#include <math.h>

#define HDIM 768
#define NG   192        // HDIM/4 float4 groups
#define LMAX 512

__device__ __forceinline__ float dot4(const float4 a, const float4 b) {
  return a.x * b.x + a.y * b.y + a.z * b.z + a.w * b.w;
}
__device__ __forceinline__ void fma4(float4& a, const float s, const float4 b) {
  a.x += s * b.x; a.y += s * b.y; a.z += s * b.z; a.w += s * b.w;
}
__device__ __forceinline__ void scale4(float4& a, const float s) {
  a.x *= s; a.y *= s; a.z *= s; a.w *= s;
}

// ---------------- kernel 0: input-width detection (slot writes) ----------------
__global__ __launch_bounds__(256) void detect_slots(const unsigned* __restrict__ mask_w,
                                                    const unsigned* __restrict__ smap_w,
                                                    unsigned* __restrict__ slots,
                                                    int mask_words, int smap_words) {
  __shared__ unsigned red[2];
  const int b = blockIdx.x, tid = threadIdx.x;
  if (tid < 2) red[tid] = 0;
  __syncthreads();
  const int gtid = b * 256 + tid, gsz = gridDim.x * 256;
  unsigned acc = 0;
  for (int i = gtid; i < mask_words / 2; i += gsz) acc |= mask_w[2 * i + 1];
  unsigned acc2 = 0;
  for (int i = gtid; i < smap_words / 2; i += gsz) acc2 |= smap_w[2 * i + 1];
  if (acc)  atomicOr(&red[0], 1u);
  if (acc2) atomicOr(&red[1], 1u);
  __syncthreads();
  if (tid == 0) { slots[b] = red[0]; slots[64 + b] = red[1]; }
}

// ---------------- kernel 1: Wc = Wq^T * Wk, c0 = bq * Wk ----------------
__global__ __launch_bounds__(256) void prep_wc(const float* __restrict__ Wq,
                                               const float* __restrict__ Wk,
                                               const float* __restrict__ bq,
                                               float* __restrict__ Wc,
                                               float* __restrict__ c0, int H) {
  __shared__ float As[16][33];
  __shared__ float Bs[16][65];
  __shared__ float bqs[16];
  const int i0 = blockIdx.x * 32, j0 = blockIdx.y * 64;
  const int idx = threadIdx.x;
  const int li = idx & 31, lk = idx >> 5;
  const int lj = idx & 63, lk2 = idx >> 6;
  const int tc = idx & 15, tr = idx >> 4;
  float c[2][4] = {{0.f,0.f,0.f,0.f},{0.f,0.f,0.f,0.f}};
  float cb[4] = {0.f,0.f,0.f,0.f};
  const bool bias_lane = (blockIdx.x == 0) && (tr == 0);
  for (int o0 = 0; o0 < H; o0 += 16) {
    __syncthreads();
    As[lk][li]       = Wq[(size_t)(o0 + lk) * H + i0 + li];
    As[lk + 8][li]   = Wq[(size_t)(o0 + lk + 8) * H + i0 + li];
    Bs[lk2][lj]      = Wk[(size_t)(o0 + lk2) * H + j0 + lj];
    Bs[lk2 + 4][lj]  = Wk[(size_t)(o0 + lk2 + 4) * H + j0 + lj];
    Bs[lk2 + 8][lj]  = Wk[(size_t)(o0 + lk2 + 8) * H + j0 + lj];
    Bs[lk2 + 12][lj] = Wk[(size_t)(o0 + lk2 + 12) * H + j0 + lj];
    if (idx < 16) bqs[idx] = bq[o0 + idx];
    __syncthreads();
#pragma unroll
    for (int k = 0; k < 16; ++k) {
      const float a0 = As[k][tr * 2], a1 = As[k][tr * 2 + 1];
      const float b0 = Bs[k][tc * 4],     b1 = Bs[k][tc * 4 + 1];
      const float b2 = Bs[k][tc * 4 + 2], b3 = Bs[k][tc * 4 + 3];
      c[0][0] += a0 * b0; c[0][1] += a0 * b1; c[0][2] += a0 * b2; c[0][3] += a0 * b3;
      c[1][0] += a1 * b0; c[1][1] += a1 * b1; c[1][2] += a1 * b2; c[1][3] += a1 * b3;
      if (bias_lane) {
        const float bv = bqs[k];
        cb[0] += bv * b0; cb[1] += bv * b1; cb[2] += bv * b2; cb[3] += bv * b3;
      }
    }
  }
#pragma unroll
  for (int j = 0; j < 4; ++j) {
    Wc[(size_t)(i0 + tr * 2) * H + j0 + tc * 4 + j]     = c[0][j];
    Wc[(size_t)(i0 + tr * 2 + 1) * H + j0 + tc * 4 + j] = c[1][j];
  }
  if (bias_lane) {
#pragma unroll
    for (int j = 0; j < 4; ++j) c0[j0 + tc * 4 + j] = cb[j];
  }
}

// ---------------- kernel 2: fused mean -> GEMV -> scores/softmax/pool ----------------
// One block per n, 384 threads. Pass 1: forward mean (16-deep load pipeline).
// GEMV: float4-coalesced Wc reads, even/odd row split + LDS combine; pass-2's
// first two batch loads are issued BEFORE the GEMV so HBM stays busy during it.
// Pass 2: r6's proven 2-buffer descending-interleaved wave-local online softmax.
__global__ __launch_bounds__(384) void fused(const float* __restrict__ hs,
                                             const unsigned* __restrict__ mask_w,
                                             const float* __restrict__ Wc,
                                             const float* __restrict__ c0,
                                             const unsigned* __restrict__ slots,
                                             float* __restrict__ pooled, int L) {
  __shared__ float4 red2[NG];
  __shared__ float4 meanv4[NG];
  __shared__ float4 vv4[NG];
  __shared__ float4 redv4[6][NG];
  __shared__ float mw[6], sw[6];
  __shared__ int   mrow[LMAX];
  __shared__ unsigned mfl;
  const int n = blockIdx.x, tid = threadIdx.x;
  const int w = tid >> 6, lane = tid & 63;

  if (tid == 0) mfl = 0u;
  __syncthreads();
  if (tid < 64 && slots[tid]) atomicOr(&mfl, 1u);

  // ---- pass 1: mean over L (forward stream, 16 loads in flight) ----
  const int half = tid / NG, t = tid - half * NG;
  const float4* hb = reinterpret_cast<const float4*>(hs) + (size_t)n * L * NG;
  float ax = 0.f, ay = 0.f, az = 0.f, aw = 0.f;
  int l = half;
  for (; l + 32 <= L; l += 32) {
    float4 u[16];
#pragma unroll
    for (int i = 0; i < 16; ++i) u[i] = hb[(size_t)(l + 2 * i) * NG + t];
#pragma unroll
    for (int i = 0; i < 16; ++i) { ax += u[i].x; ay += u[i].y; az += u[i].z; aw += u[i].w; }
  }
  for (; l < L; l += 2) {
    float4 u = hb[(size_t)l * NG + t];
    ax += u.x; ay += u.y; az += u.z; aw += u.w;
  }
  if (half == 1) { float4 o; o.x = ax; o.y = ay; o.z = az; o.w = aw; red2[t] = o; }
  __syncthreads();

  if (half == 0) {
    const float inv = 1.0f / (float)L;
    const float4 r = red2[t];
    float4 o;
    o.x = (ax + r.x) * inv; o.y = (ay + r.y) * inv;
    o.z = (az + r.z) * inv; o.w = (aw + r.w) * inv;
    meanv4[t] = o;
  }
  const int mask_is_i32 = (mfl != 0);
  for (int tt = tid; tt < L; tt += 384) {
    const size_t idx = (size_t)n * L + tt;
    mrow[tt] = (int)(mask_is_i32 ? mask_w[idx] : mask_w[2 * idx]);
  }
  __syncthreads();   // meanv, mrow ready; red2 free for reuse

  // ---- pass-2 state + EARLY PREFETCH (before GEMV) ----
  const float scale = 1.0f / sqrtf((float)HDIM);
  const int cnt = (L - 1 - w) / 6 + 1;      // row-slots this wave owns (85/86)
  float m = -3.0e38f, ss = 0.f;
  float4 A0 = {0,0,0,0}, A1 = {0,0,0,0}, A2 = {0,0,0,0};
  float4 xa[2][3], xb[2][3];
  float4 vf0, vf1, vf2;                     // assigned after GEMV

  auto ld = [&](float4 (&X)[2][3], int j) {
#pragma unroll
    for (int u = 0; u < 2; ++u) {
      const int jj = j + u;
      const int rr = (jj < cnt) ? (L - 1 - 6 * jj - w) : 0;
      const float4* rp = hb + (size_t)rr * NG;
      X[u][0] = rp[lane]; X[u][1] = rp[64 + lane]; X[u][2] = rp[128 + lane];
    }
  };
  ld(xa, 0);   // slots 0,1 in flight across the GEMV
  ld(xb, 2);   // slots 2,3

  // ---- GEMV: v = mean * Wc + c0 (float4 rows of Wc; even/odd split) ----
  {
    const int par = tid / NG, g = tid - par * NG;
    const float* mv = (const float*)meanv4;
    const float4* Wc4 = reinterpret_cast<const float4*>(Wc);
    float4 va = {0.f, 0.f, 0.f, 0.f};
#pragma unroll 4
    for (int o = par; o < HDIM; o += 2) {
      const float mo = mv[o];
      const float4 wr = Wc4[(size_t)o * NG + g];
      va.x += mo * wr.x; va.y += mo * wr.y; va.z += mo * wr.z; va.w += mo * wr.w;
    }
    if (par == 1) red2[g] = va;
    __syncthreads();
    if (par == 0) {
      const float4 r = red2[g];
      const float4 cc = reinterpret_cast<const float4*>(c0)[g];
      float4 o4;
      o4.x = va.x + r.x + cc.x; o4.y = va.y + r.y + cc.y;
      o4.z = va.z + r.z + cc.z; o4.w = va.w + r.w + cc.w;
      vv4[g] = o4;
    }
    __syncthreads();
  }
  vf0 = vv4[lane]; vf1 = vv4[64 + lane]; vf2 = vv4[128 + lane];

  // ---- pass 2: 2-buffer pipeline (r6 schedule, loads one phase deeper) ----
  auto pr = [&](float4 (&X)[2][3], int j) {
    float s[2]; 
#pragma unroll
    for (int u = 0; u < 2; ++u) {
      const int jj = j + u;
      const int r = L - 1 - 6 * jj - w;
      float p = dot4(X[u][0], vf0) + dot4(X[u][1], vf1) + dot4(X[u][2], vf2);
#pragma unroll
      for (int off = 32; off > 0; off >>= 1) p += __shfl_xor(p, off, 64);
      s[u] = (jj >= cnt || mrow[r & (LMAX - 1)] == 0) ? -1e9f : p * scale;
    }
    const float mc = fmaxf(s[0], s[1]);
    if (mc > m) {   // defer-rescale (wave-uniform)
      const float f = __expf(m - mc);
      ss *= f; scale4(A0, f); scale4(A1, f); scale4(A2, f);
      m = mc;
    }
#pragma unroll
    for (int u = 0; u < 2; ++u) {
      const float pq = (j + u < cnt) ? __expf(s[u] - m) : 0.f;
      ss += pq;
      fma4(A0, pq, X[u][0]); fma4(A1, pq, X[u][1]); fma4(A2, pq, X[u][2]);
    }
  };

  for (int j = 0; j < 88; j += 4) {   // 88 slots >= max cnt 86
    pr(xa, j);
    if (j + 4 < 88) ld(xa, j + 4);
    pr(xb, j + 2);
    if (j + 6 < 88) ld(xb, j + 6);
  }

  // ---- 6-way split-softmax merge ----
  if (lane == 0) { mw[w] = m; sw[w] = ss; }
  redv4[w][lane]       = A0;
  redv4[w][64 + lane]  = A1;
  redv4[w][128 + lane] = A2;
  __syncthreads();
  float M = mw[0];
#pragma unroll
  for (int j = 1; j < 6; ++j) M = fmaxf(M, mw[j]);
  float f[6], S = 0.f;
#pragma unroll
  for (int j = 0; j < 6; ++j) { f[j] = __expf(mw[j] - M); S += sw[j] * f[j]; }
  const float invS = 1.0f / S;
  const float* redp = (const float*)redv4;
#pragma unroll
  for (int part = 0; part < 2; ++part) {
    const int col = part * 384 + tid;
    float o = 0.f;
#pragma unroll
    for (int j = 0; j < 6; ++j) o += redp[j * HDIM + col] * f[j];
    pooled[(size_t)n * HDIM + col] = o * invS;
  }
}

// ---------------- kernel 3: segment mean ----------------
__global__ __launch_bounds__(256) void segmean(const float* __restrict__ pooled,
                                               const void* __restrict__ smap,
                                               const unsigned* __restrict__ slots_s,
                                               float* __restrict__ out, int N) {
  __shared__ unsigned fsh;
  const int t = blockIdx.x, tid = threadIdx.x;
  const int col = blockIdx.y * 256 + tid;
  if (tid == 0) {
    unsigned f = 0;
    for (int i = 0; i < 64; ++i) f |= slots_s[i];
    fsh = f;
  }
  __syncthreads();
  const int smap_is_i32 = (fsh != 0);
  float a = 0.f;
  int cnt = 0;
  for (int i = 0; i < N; ++i) {
    const int s = smap_is_i32 ? ((const int*)smap)[i]
                              : (int)((const long long*)smap)[i];
    if (s == t) { a += pooled[(size_t)i * HDIM + col]; ++cnt; }
  }
  out[(size_t)t * HDIM + col] = a / (float)(cnt > 0 ? cnt : 1);
}

extern "C" void kernel_launch(void* const* d_in, const int* in_sizes, int n_in,
                              void* d_out, int out_size, void* d_ws, size_t ws_size,
                              hipStream_t stream) {
  const float*    hs     = (const float*)d_in[0];
  const unsigned* mask_w = (const unsigned*)d_in[1];
  const void*     smap   = d_in[2];
  const float*    Wq     = (const float*)d_in[3];
  const float*    bq     = (const float*)d_in[4];
  const float*    Wk     = (const float*)d_in[5];
  // d_in[6] = bk: dead (adds per-row constant to scores -> softmax-invariant)

  const int N = in_sizes[2];           // 512
  const int L = in_sizes[1] / N;       // 512
  const int H = in_sizes[4];           // 768 (== HDIM)
  const int T = out_size / H;          // 32

  float* Wc     = (float*)d_ws;                    // [H,H]
  float* c0     = Wc + (size_t)H * H;              // [H]
  float* pooled = c0 + H;                          // [N,H]
  unsigned* slots = (unsigned*)(pooled + (size_t)N * H);  // [128]
  (void)ws_size; (void)n_in;

  detect_slots<<<64, 256, 0, stream>>>(mask_w, (const unsigned*)smap, slots, N * L, N);
  prep_wc<<<dim3(H / 32, H / 64), 256, 0, stream>>>(Wq, Wk, bq, Wc, c0, H);
  fused<<<N, 384, 0, stream>>>(hs, mask_w, Wc, c0, slots, pooled, L);
  segmean<<<dim3(T, 3), 256, 0, stream>>>(pooled, smap, slots + 64, (float*)d_out, N);
}

// Round 10
// 418.499 us; speedup vs baseline: 1.1098x; 1.0358x over previous
//
#include <hip/hip_runtime.h>
#include <math.h>

#define HDIM 768
#define NG   192        // HDIM/4 float4 groups
#define LMAX 512

__device__ __forceinline__ float dot4(const float4 a, const float4 b) {
  return a.x * b.x + a.y * b.y + a.z * b.z + a.w * b.w;
}
__device__ __forceinline__ void fma4(float4& a, const float s, const float4 b) {
  a.x += s * b.x; a.y += s * b.y; a.z += s * b.z; a.w += s * b.w;
}
__device__ __forceinline__ void scale4(float4& a, const float s) {
  a.x *= s; a.y *= s; a.z *= s; a.w *= s;
}

// Wave64 sum via DPP (VALU pipe only — no ds_swizzle/bpermute latency).
// quad_perm xor1, xor2 -> quad sums; row_ror:4, :8 -> row-of-16 sums;
// row_bcast15/31 chain partial row sums downward; lane 63 holds the total.
__device__ __forceinline__ float wave_sum64(float x) {
  x += __int_as_float(__builtin_amdgcn_update_dpp(0, __float_as_int(x), 0xB1,  0xF, 0xF, true)); // quad_perm [1,0,3,2]
  x += __int_as_float(__builtin_amdgcn_update_dpp(0, __float_as_int(x), 0x4E,  0xF, 0xF, true)); // quad_perm [2,3,0,1]
  x += __int_as_float(__builtin_amdgcn_update_dpp(0, __float_as_int(x), 0x124, 0xF, 0xF, true)); // row_ror:4
  x += __int_as_float(__builtin_amdgcn_update_dpp(0, __float_as_int(x), 0x128, 0xF, 0xF, true)); // row_ror:8
  x += __int_as_float(__builtin_amdgcn_update_dpp(0, __float_as_int(x), 0x142, 0xF, 0xF, true)); // row_bcast15
  x += __int_as_float(__builtin_amdgcn_update_dpp(0, __float_as_int(x), 0x143, 0xF, 0xF, true)); // row_bcast31
  return __int_as_float(__builtin_amdgcn_readlane(__float_as_int(x), 63));
}

// ---------------- kernel 0: input-width detection (slot writes) ----------------
__global__ __launch_bounds__(256) void detect_slots(const unsigned* __restrict__ mask_w,
                                                    const unsigned* __restrict__ smap_w,
                                                    unsigned* __restrict__ slots,
                                                    int mask_words, int smap_words) {
  __shared__ unsigned red[2];
  const int b = blockIdx.x, tid = threadIdx.x;
  if (tid < 2) red[tid] = 0;
  __syncthreads();
  const int gtid = b * 256 + tid, gsz = gridDim.x * 256;
  unsigned acc = 0;
  for (int i = gtid; i < mask_words / 2; i += gsz) acc |= mask_w[2 * i + 1];
  unsigned acc2 = 0;
  for (int i = gtid; i < smap_words / 2; i += gsz) acc2 |= smap_w[2 * i + 1];
  if (acc)  atomicOr(&red[0], 1u);
  if (acc2) atomicOr(&red[1], 1u);
  __syncthreads();
  if (tid == 0) { slots[b] = red[0]; slots[64 + b] = red[1]; }
}

// ---------------- kernel 1: Wc = Wq^T * Wk, c0 = bq * Wk ----------------
__global__ __launch_bounds__(256) void prep_wc(const float* __restrict__ Wq,
                                               const float* __restrict__ Wk,
                                               const float* __restrict__ bq,
                                               float* __restrict__ Wc,
                                               float* __restrict__ c0, int H) {
  __shared__ float As[16][33];
  __shared__ float Bs[16][65];
  __shared__ float bqs[16];
  const int i0 = blockIdx.x * 32, j0 = blockIdx.y * 64;
  const int idx = threadIdx.x;
  const int li = idx & 31, lk = idx >> 5;
  const int lj = idx & 63, lk2 = idx >> 6;
  const int tc = idx & 15, tr = idx >> 4;
  float c[2][4] = {{0.f,0.f,0.f,0.f},{0.f,0.f,0.f,0.f}};
  float cb[4] = {0.f,0.f,0.f,0.f};
  const bool bias_lane = (blockIdx.x == 0) && (tr == 0);
  for (int o0 = 0; o0 < H; o0 += 16) {
    __syncthreads();
    As[lk][li]       = Wq[(size_t)(o0 + lk) * H + i0 + li];
    As[lk + 8][li]   = Wq[(size_t)(o0 + lk + 8) * H + i0 + li];
    Bs[lk2][lj]      = Wk[(size_t)(o0 + lk2) * H + j0 + lj];
    Bs[lk2 + 4][lj]  = Wk[(size_t)(o0 + lk2 + 4) * H + j0 + lj];
    Bs[lk2 + 8][lj]  = Wk[(size_t)(o0 + lk2 + 8) * H + j0 + lj];
    Bs[lk2 + 12][lj] = Wk[(size_t)(o0 + lk2 + 12) * H + j0 + lj];
    if (idx < 16) bqs[idx] = bq[o0 + idx];
    __syncthreads();
#pragma unroll
    for (int k = 0; k < 16; ++k) {
      const float a0 = As[k][tr * 2], a1 = As[k][tr * 2 + 1];
      const float b0 = Bs[k][tc * 4],     b1 = Bs[k][tc * 4 + 1];
      const float b2 = Bs[k][tc * 4 + 2], b3 = Bs[k][tc * 4 + 3];
      c[0][0] += a0 * b0; c[0][1] += a0 * b1; c[0][2] += a0 * b2; c[0][3] += a0 * b3;
      c[1][0] += a1 * b0; c[1][1] += a1 * b1; c[1][2] += a1 * b2; c[1][3] += a1 * b3;
      if (bias_lane) {
        const float bv = bqs[k];
        cb[0] += bv * b0; cb[1] += bv * b1; cb[2] += bv * b2; cb[3] += bv * b3;
      }
    }
  }
#pragma unroll
  for (int j = 0; j < 4; ++j) {
    Wc[(size_t)(i0 + tr * 2) * H + j0 + tc * 4 + j]     = c[0][j];
    Wc[(size_t)(i0 + tr * 2 + 1) * H + j0 + tc * 4 + j] = c[1][j];
  }
  if (bias_lane) {
#pragma unroll
    for (int j = 0; j < 4; ++j) c0[j0 + tc * 4 + j] = cb[j];
  }
}

// ---------------- kernel 2: fused mean -> GEMV -> scores/softmax/pool ----------------
// r6 structure exactly; ONLY the cross-lane score reduce is replaced by the
// DPP-based wave_sum64 (VALU pipe, ~40cy chain vs ~240cy of serialized
// ds_swizzle shuffles).
__global__ __launch_bounds__(384) void fused(const float* __restrict__ hs,
                                             const unsigned* __restrict__ mask_w,
                                             const float* __restrict__ Wc,
                                             const float* __restrict__ c0,
                                             const unsigned* __restrict__ slots,
                                             float* __restrict__ pooled, int L) {
  __shared__ float4 red2[NG];
  __shared__ float4 meanv4[NG];
  __shared__ float4 vv4[NG];
  __shared__ float4 redv4[6][NG];
  __shared__ float mw[6], sw[6];
  __shared__ int   mrow[LMAX];
  __shared__ unsigned mfl;
  const int n = blockIdx.x, tid = threadIdx.x;
  const int w = tid >> 6, lane = tid & 63;

  if (tid == 0) mfl = 0u;
  __syncthreads();
  if (tid < 64 && slots[tid]) atomicOr(&mfl, 1u);

  // ---- pass 1: mean over L (forward stream) ----
  const int half = tid / NG, t = tid - half * NG;
  const float4* hb = reinterpret_cast<const float4*>(hs) + (size_t)n * L * NG;
  float ax = 0.f, ay = 0.f, az = 0.f, aw = 0.f;
  int l = half;
  for (; l + 16 <= L; l += 16) {
    float4 u[8];
#pragma unroll
    for (int i = 0; i < 8; ++i) u[i] = hb[(size_t)(l + 2 * i) * NG + t];
#pragma unroll
    for (int i = 0; i < 8; ++i) { ax += u[i].x; ay += u[i].y; az += u[i].z; aw += u[i].w; }
  }
  for (; l < L; l += 2) {
    float4 u = hb[(size_t)l * NG + t];
    ax += u.x; ay += u.y; az += u.z; aw += u.w;
  }
  if (half == 1) { float4 o; o.x = ax; o.y = ay; o.z = az; o.w = aw; red2[t] = o; }
  __syncthreads();

  if (half == 0) {
    const float inv = 1.0f / (float)L;
    const float4 r = red2[t];
    float4 o;
    o.x = (ax + r.x) * inv; o.y = (ay + r.y) * inv;
    o.z = (az + r.z) * inv; o.w = (aw + r.w) * inv;
    meanv4[t] = o;
  }
  const int mask_is_i32 = (mfl != 0);
  for (int tt = tid; tt < L; tt += 384) {
    const size_t idx = (size_t)n * L + tt;
    mrow[tt] = (int)(mask_is_i32 ? mask_w[idx] : mask_w[2 * idx]);
  }
  __syncthreads();

  // ---- GEMV: v = mean * Wc + c0 ----
  {
    const int c1 = tid, c2 = tid + 384;
    float acc1 = 0.f, acc2 = 0.f;
    const float* wp = Wc;
    for (int o = 0; o < HDIM; o += 4) {
      const float4 mv = meanv4[o >> 2];
      acc1 += mv.x * wp[c1] + mv.y * wp[HDIM + c1] + mv.z * wp[2 * HDIM + c1] + mv.w * wp[3 * HDIM + c1];
      acc2 += mv.x * wp[c2] + mv.y * wp[HDIM + c2] + mv.z * wp[2 * HDIM + c2] + mv.w * wp[3 * HDIM + c2];
      wp += 4 * HDIM;
    }
    ((float*)vv4)[c1] = acc1 + c0[c1];
    ((float*)vv4)[c2] = acc2 + c0[c2];
  }
  __syncthreads();

  // ---- pass 2: descending interleaved rows, wave-local online softmax ----
  const float4 vf0 = vv4[lane], vf1 = vv4[64 + lane], vf2 = vv4[128 + lane];
  const float scale = 1.0f / sqrtf((float)HDIM);
  const int cnt = (L - 1 - w) / 6 + 1;      // row-slots this wave owns (85/86)
  float m = -3.0e38f, ss = 0.f;
  float4 A0 = {0,0,0,0}, A1 = {0,0,0,0}, A2 = {0,0,0,0};
  float4 xa[2][3], xb[2][3];

  auto ld = [&](float4 (&X)[2][3], int j) {
#pragma unroll
    for (int u = 0; u < 2; ++u) {
      const int jj = j + u;
      const int rr = (jj < cnt) ? (L - 1 - 6 * jj - w) : 0;
      const float4* rp = hb + (size_t)rr * NG;
      X[u][0] = rp[lane]; X[u][1] = rp[64 + lane]; X[u][2] = rp[128 + lane];
    }
  };
  auto pr = [&](float4 (&X)[2][3], int j) {
    float s[2];
#pragma unroll
    for (int u = 0; u < 2; ++u) {
      const int jj = j + u;
      const int r = L - 1 - 6 * jj - w;
      const float p = wave_sum64(dot4(X[u][0], vf0) + dot4(X[u][1], vf1) + dot4(X[u][2], vf2));
      s[u] = (jj >= cnt || mrow[r & (LMAX - 1)] == 0) ? -1e9f : p * scale;
    }
    const float mc = fmaxf(s[0], s[1]);
    if (mc > m) {   // defer-rescale (wave-uniform)
      const float f = __expf(m - mc);
      ss *= f; scale4(A0, f); scale4(A1, f); scale4(A2, f);
      m = mc;
    }
#pragma unroll
    for (int u = 0; u < 2; ++u) {
      const float pq = (j + u < cnt) ? __expf(s[u] - m) : 0.f;
      ss += pq;
      fma4(A0, pq, X[u][0]); fma4(A1, pq, X[u][1]); fma4(A2, pq, X[u][2]);
    }
  };

  ld(xa, 0);
  for (int j = 0; j < 88; j += 4) {   // 88 slots >= max cnt 86
    ld(xb, j + 2);
    pr(xa, j);
    if (j + 4 < 88) ld(xa, j + 4);
    pr(xb, j + 2);
  }

  // ---- 6-way split-softmax merge ----
  if (lane == 0) { mw[w] = m; sw[w] = ss; }
  redv4[w][lane]       = A0;
  redv4[w][64 + lane]  = A1;
  redv4[w][128 + lane] = A2;
  __syncthreads();
  float M = mw[0];
#pragma unroll
  for (int j = 1; j < 6; ++j) M = fmaxf(M, mw[j]);
  float f[6], S = 0.f;
#pragma unroll
  for (int j = 0; j < 6; ++j) { f[j] = __expf(mw[j] - M); S += sw[j] * f[j]; }
  const float invS = 1.0f / S;
  const float* redp = (const float*)redv4;
#pragma unroll
  for (int part = 0; part < 2; ++part) {
    const int col = part * 384 + tid;
    float o = 0.f;
#pragma unroll
    for (int j = 0; j < 6; ++j) o += redp[j * HDIM + col] * f[j];
    pooled[(size_t)n * HDIM + col] = o * invS;
  }
}

// ---------------- kernel 3: segment mean ----------------
__global__ __launch_bounds__(256) void segmean(const float* __restrict__ pooled,
                                               const void* __restrict__ smap,
                                               const unsigned* __restrict__ slots_s,
                                               float* __restrict__ out, int N) {
  __shared__ unsigned fsh;
  const int t = blockIdx.x, tid = threadIdx.x;
  const int col = blockIdx.y * 256 + tid;
  if (tid == 0) {
    unsigned f = 0;
    for (int i = 0; i < 64; ++i) f |= slots_s[i];
    fsh = f;
  }
  __syncthreads();
  const int smap_is_i32 = (fsh != 0);
  float a = 0.f;
  int cnt = 0;
  for (int i = 0; i < N; ++i) {
    const int s = smap_is_i32 ? ((const int*)smap)[i]
                              : (int)((const long long*)smap)[i];
    if (s == t) { a += pooled[(size_t)i * HDIM + col]; ++cnt; }
  }
  out[(size_t)t * HDIM + col] = a / (float)(cnt > 0 ? cnt : 1);
}

extern "C" void kernel_launch(void* const* d_in, const int* in_sizes, int n_in,
                              void* d_out, int out_size, void* d_ws, size_t ws_size,
                              hipStream_t stream) {
  const float*    hs     = (const float*)d_in[0];
  const unsigned* mask_w = (const unsigned*)d_in[1];
  const void*     smap   = d_in[2];
  const float*    Wq     = (const float*)d_in[3];
  const float*    bq     = (const float*)d_in[4];
  const float*    Wk     = (const float*)d_in[5];
  // d_in[6] = bk: dead (adds per-row constant to scores -> softmax-invariant)

  const int N = in_sizes[2];           // 512
  const int L = in_sizes[1] / N;       // 512
  const int H = in_sizes[4];           // 768 (== HDIM)
  const int T = out_size / H;          // 32

  float* Wc     = (float*)d_ws;                    // [H,H]
  float* c0     = Wc + (size_t)H * H;              // [H]
  float* pooled = c0 + H;                          // [N,H]
  unsigned* slots = (unsigned*)(pooled + (size_t)N * H);  // [128]
  (void)ws_size; (void)n_in;

  detect_slots<<<64, 256, 0, stream>>>(mask_w, (const unsigned*)smap, slots, N * L, N);
  prep_wc<<<dim3(H / 32, H / 64), 256, 0, stream>>>(Wq, Wk, bq, Wc, c0, H);
  fused<<<N, 384, 0, stream>>>(hs, mask_w, Wc, c0, slots, pooled, L);
  segmean<<<dim3(T, 3), 256, 0, stream>>>(pooled, smap, slots + 64, (float*)d_out, N);
}

// Round 11
// 367.630 us; speedup vs baseline: 1.2634x; 1.1384x over previous
//
#include <hip/hip_runtime.h>
#include <math.h>

#define HDIM 768
#define NG   192        // HDIM/4 float4 groups
#define LMAX 512

__device__ __forceinline__ float dot4(const float4 a, const float4 b) {
  return a.x * b.x + a.y * b.y + a.z * b.z + a.w * b.w;
}
__device__ __forceinline__ void fma4(float4& a, const float s, const float4 b) {
  a.x += s * b.x; a.y += s * b.y; a.z += s * b.z; a.w += s * b.w;
}
__device__ __forceinline__ void scale4(float4& a, const float s) {
  a.x *= s; a.y *= s; a.z *= s; a.w *= s;
}

// Wave64 sum via DPP (VALU pipe only).
__device__ __forceinline__ float wave_sum64(float x) {
  x += __int_as_float(__builtin_amdgcn_update_dpp(0, __float_as_int(x), 0xB1,  0xF, 0xF, true)); // quad_perm [1,0,3,2]
  x += __int_as_float(__builtin_amdgcn_update_dpp(0, __float_as_int(x), 0x4E,  0xF, 0xF, true)); // quad_perm [2,3,0,1]
  x += __int_as_float(__builtin_amdgcn_update_dpp(0, __float_as_int(x), 0x124, 0xF, 0xF, true)); // row_ror:4
  x += __int_as_float(__builtin_amdgcn_update_dpp(0, __float_as_int(x), 0x128, 0xF, 0xF, true)); // row_ror:8
  x += __int_as_float(__builtin_amdgcn_update_dpp(0, __float_as_int(x), 0x142, 0xF, 0xF, true)); // row_bcast15
  x += __int_as_float(__builtin_amdgcn_update_dpp(0, __float_as_int(x), 0x143, 0xF, 0xF, true)); // row_bcast31
  return __int_as_float(__builtin_amdgcn_readlane(__float_as_int(x), 63));
}

// ---------------- kernel 0: input-width detection (slot writes) ----------------
__global__ __launch_bounds__(256) void detect_slots(const unsigned* __restrict__ mask_w,
                                                    const unsigned* __restrict__ smap_w,
                                                    unsigned* __restrict__ slots,
                                                    int mask_words, int smap_words) {
  __shared__ unsigned red[2];
  const int b = blockIdx.x, tid = threadIdx.x;
  if (tid < 2) red[tid] = 0;
  __syncthreads();
  const int gtid = b * 256 + tid, gsz = gridDim.x * 256;
  unsigned acc = 0;
  for (int i = gtid; i < mask_words / 2; i += gsz) acc |= mask_w[2 * i + 1];
  unsigned acc2 = 0;
  for (int i = gtid; i < smap_words / 2; i += gsz) acc2 |= smap_w[2 * i + 1];
  if (acc)  atomicOr(&red[0], 1u);
  if (acc2) atomicOr(&red[1], 1u);
  __syncthreads();
  if (tid == 0) { slots[b] = red[0]; slots[64 + b] = red[1]; }
}

// ---------------- kernel 1: Wc = Wq^T * Wk, c0 = bq * Wk ----------------
__global__ __launch_bounds__(256) void prep_wc(const float* __restrict__ Wq,
                                               const float* __restrict__ Wk,
                                               const float* __restrict__ bq,
                                               float* __restrict__ Wc,
                                               float* __restrict__ c0, int H) {
  __shared__ float As[16][33];
  __shared__ float Bs[16][65];
  __shared__ float bqs[16];
  const int i0 = blockIdx.x * 32, j0 = blockIdx.y * 64;
  const int idx = threadIdx.x;
  const int li = idx & 31, lk = idx >> 5;
  const int lj = idx & 63, lk2 = idx >> 6;
  const int tc = idx & 15, tr = idx >> 4;
  float c[2][4] = {{0.f,0.f,0.f,0.f},{0.f,0.f,0.f,0.f}};
  float cb[4] = {0.f,0.f,0.f,0.f};
  const bool bias_lane = (blockIdx.x == 0) && (tr == 0);
  for (int o0 = 0; o0 < H; o0 += 16) {
    __syncthreads();
    As[lk][li]       = Wq[(size_t)(o0 + lk) * H + i0 + li];
    As[lk + 8][li]   = Wq[(size_t)(o0 + lk + 8) * H + i0 + li];
    Bs[lk2][lj]      = Wk[(size_t)(o0 + lk2) * H + j0 + lj];
    Bs[lk2 + 4][lj]  = Wk[(size_t)(o0 + lk2 + 4) * H + j0 + lj];
    Bs[lk2 + 8][lj]  = Wk[(size_t)(o0 + lk2 + 8) * H + j0 + lj];
    Bs[lk2 + 12][lj] = Wk[(size_t)(o0 + lk2 + 12) * H + j0 + lj];
    if (idx < 16) bqs[idx] = bq[o0 + idx];
    __syncthreads();
#pragma unroll
    for (int k = 0; k < 16; ++k) {
      const float a0 = As[k][tr * 2], a1 = As[k][tr * 2 + 1];
      const float b0 = Bs[k][tc * 4],     b1 = Bs[k][tc * 4 + 1];
      const float b2 = Bs[k][tc * 4 + 2], b3 = Bs[k][tc * 4 + 3];
      c[0][0] += a0 * b0; c[0][1] += a0 * b1; c[0][2] += a0 * b2; c[0][3] += a0 * b3;
      c[1][0] += a1 * b0; c[1][1] += a1 * b1; c[1][2] += a1 * b2; c[1][3] += a1 * b3;
      if (bias_lane) {
        const float bv = bqs[k];
        cb[0] += bv * b0; cb[1] += bv * b1; cb[2] += bv * b2; cb[3] += bv * b3;
      }
    }
  }
#pragma unroll
  for (int j = 0; j < 4; ++j) {
    Wc[(size_t)(i0 + tr * 2) * H + j0 + tc * 4 + j]     = c[0][j];
    Wc[(size_t)(i0 + tr * 2 + 1) * H + j0 + tc * 4 + j] = c[1][j];
  }
  if (bias_lane) {
#pragma unroll
    for (int j = 0; j < 4; ++j) c0[j0 + tc * 4 + j] = cb[j];
  }
}

// ---------------- kernel 2: fused mean -> GEMV -> scores/softmax/pool ----------------
// r10 structure; pass 2 now iterates ONLY valid (unmasked) rows via a
// deterministic ballot-compacted index list (masked rows have softmax weight
// exactly 0 in fp32/fp64 -> skipping them is exact). ~50% of pass-2 traffic gone.
__global__ __launch_bounds__(384) void fused(const float* __restrict__ hs,
                                             const unsigned* __restrict__ mask_w,
                                             const float* __restrict__ Wc,
                                             const float* __restrict__ c0,
                                             const unsigned* __restrict__ slots,
                                             float* __restrict__ pooled, int L) {
  __shared__ float4 red2[NG];
  __shared__ float4 meanv4[NG];
  __shared__ float4 vv4[NG];
  __shared__ float4 redv4[6][NG];
  __shared__ float mw[6], sw[6];
  __shared__ int   mrow[LMAX];
  __shared__ int   vidx[LMAX];
  __shared__ int   nv_sh;
  __shared__ unsigned mfl;
  const int n = blockIdx.x, tid = threadIdx.x;
  const int w = tid >> 6, lane = tid & 63;

  if (tid == 0) mfl = 0u;
  __syncthreads();
  if (tid < 64 && slots[tid]) atomicOr(&mfl, 1u);

  // ---- pass 1: mean over L (forward stream) ----
  const int half = tid / NG, t = tid - half * NG;
  const float4* hb = reinterpret_cast<const float4*>(hs) + (size_t)n * L * NG;
  float ax = 0.f, ay = 0.f, az = 0.f, aw = 0.f;
  int l = half;
  for (; l + 16 <= L; l += 16) {
    float4 u[8];
#pragma unroll
    for (int i = 0; i < 8; ++i) u[i] = hb[(size_t)(l + 2 * i) * NG + t];
#pragma unroll
    for (int i = 0; i < 8; ++i) { ax += u[i].x; ay += u[i].y; az += u[i].z; aw += u[i].w; }
  }
  for (; l < L; l += 2) {
    float4 u = hb[(size_t)l * NG + t];
    ax += u.x; ay += u.y; az += u.z; aw += u.w;
  }
  if (half == 1) { float4 o; o.x = ax; o.y = ay; o.z = az; o.w = aw; red2[t] = o; }
  __syncthreads();

  if (half == 0) {
    const float inv = 1.0f / (float)L;
    const float4 r = red2[t];
    float4 o;
    o.x = (ax + r.x) * inv; o.y = (ay + r.y) * inv;
    o.z = (az + r.z) * inv; o.w = (aw + r.w) * inv;
    meanv4[t] = o;
  }
  const int mask_is_i32 = (mfl != 0);
  for (int tt = tid; tt < L; tt += 384) {
    const size_t idx = (size_t)n * L + tt;
    mrow[tt] = (int)(mask_is_i32 ? mask_w[idx] : mask_w[2 * idx]);
  }
  __syncthreads();   // meanv, mrow ready

  // ---- wave 0: deterministic compaction of valid rows (ballot scan) ----
  if (w == 0) {
    int off = 0;
    for (int seg = 0; seg < L; seg += 64) {
      const int mv = mrow[seg + lane];
      const unsigned long long bal = __ballot(mv != 0);
      const int rank = __popcll(bal & ((1ull << lane) - 1ull));
      if (mv != 0) vidx[off + rank] = seg + lane;
      off += __popcll(bal);
    }
    if (lane == 0) nv_sh = off;
  }

  // ---- GEMV: v = mean * Wc + c0 (all waves; wave 0 joins after compaction) ----
  {
    const int c1 = tid, c2 = tid + 384;
    float acc1 = 0.f, acc2 = 0.f;
    const float* wp = Wc;
    for (int o = 0; o < HDIM; o += 4) {
      const float4 mv = meanv4[o >> 2];
      acc1 += mv.x * wp[c1] + mv.y * wp[HDIM + c1] + mv.z * wp[2 * HDIM + c1] + mv.w * wp[3 * HDIM + c1];
      acc2 += mv.x * wp[c2] + mv.y * wp[HDIM + c2] + mv.z * wp[2 * HDIM + c2] + mv.w * wp[3 * HDIM + c2];
      wp += 4 * HDIM;
    }
    ((float*)vv4)[c1] = acc1 + c0[c1];
    ((float*)vv4)[c2] = acc2 + c0[c2];
  }
  __syncthreads();   // vv4, vidx, nv ready

  const int nv = nv_sh;
  if (nv == 0) {
    // all rows masked: reference softmax is uniform -> pooled = mean
#pragma unroll
    for (int part = 0; part < 2; ++part) {
      const int col = part * 384 + tid;
      pooled[(size_t)n * HDIM + col] = ((const float*)meanv4)[col];
    }
    return;
  }

  // ---- pass 2: valid rows only; wave-local online softmax (r6/r10 schedule) ----
  const float4 vf0 = vv4[lane], vf1 = vv4[64 + lane], vf2 = vv4[128 + lane];
  const float scale = 1.0f / sqrtf((float)HDIM);
  const int cntw = (nv > w) ? ((nv - 1 - w) / 6 + 1) : 0;   // compact slots this wave owns
  const int cmax = (nv + 5) / 6;
  const int jmax = (cmax + 3) & ~3;                          // multiple of 4, >= 4
  const int vidx0 = vidx[0];
  float m = -3.0e38f, ss = 0.f;
  float4 A0 = {0,0,0,0}, A1 = {0,0,0,0}, A2 = {0,0,0,0};
  float4 xa[2][3], xb[2][3];

  auto ld = [&](float4 (&X)[2][3], int j) {
#pragma unroll
    for (int u = 0; u < 2; ++u) {
      const int jj = j + u;
      const int rr = (jj < cntw) ? vidx[6 * jj + w] : vidx0;
      const float4* rp = hb + (size_t)rr * NG;
      X[u][0] = rp[lane]; X[u][1] = rp[64 + lane]; X[u][2] = rp[128 + lane];
    }
  };
  auto pr = [&](float4 (&X)[2][3], int j) {
    float s[2];
#pragma unroll
    for (int u = 0; u < 2; ++u) {
      const float p = wave_sum64(dot4(X[u][0], vf0) + dot4(X[u][1], vf1) + dot4(X[u][2], vf2));
      s[u] = (j + u < cntw) ? p * scale : -3.0e38f;
    }
    const float mc = fmaxf(s[0], s[1]);
    if (mc > m) {   // defer-rescale (wave-uniform)
      const float f = __expf(m - mc);
      ss *= f; scale4(A0, f); scale4(A1, f); scale4(A2, f);
      m = mc;
    }
#pragma unroll
    for (int u = 0; u < 2; ++u) {
      const float pq = (j + u < cntw) ? __expf(s[u] - m) : 0.f;
      ss += pq;
      fma4(A0, pq, X[u][0]); fma4(A1, pq, X[u][1]); fma4(A2, pq, X[u][2]);
    }
  };

  ld(xa, 0);
  for (int j = 0; j < jmax; j += 4) {
    ld(xb, j + 2);
    pr(xa, j);
    if (j + 4 < jmax) ld(xa, j + 4);
    pr(xb, j + 2);
  }

  // ---- 6-way split-softmax merge ----
  if (lane == 0) { mw[w] = m; sw[w] = ss; }
  redv4[w][lane]       = A0;
  redv4[w][64 + lane]  = A1;
  redv4[w][128 + lane] = A2;
  __syncthreads();
  float M = mw[0];
#pragma unroll
  for (int j = 1; j < 6; ++j) M = fmaxf(M, mw[j]);
  float f[6], S = 0.f;
#pragma unroll
  for (int j = 0; j < 6; ++j) { f[j] = __expf(mw[j] - M); S += sw[j] * f[j]; }
  const float invS = 1.0f / S;
  const float* redp = (const float*)redv4;
#pragma unroll
  for (int part = 0; part < 2; ++part) {
    const int col = part * 384 + tid;
    float o = 0.f;
#pragma unroll
    for (int j = 0; j < 6; ++j) o += redp[j * HDIM + col] * f[j];
    pooled[(size_t)n * HDIM + col] = o * invS;
  }
}

// ---------------- kernel 3: segment mean ----------------
__global__ __launch_bounds__(256) void segmean(const float* __restrict__ pooled,
                                               const void* __restrict__ smap,
                                               const unsigned* __restrict__ slots_s,
                                               float* __restrict__ out, int N) {
  __shared__ unsigned fsh;
  const int t = blockIdx.x, tid = threadIdx.x;
  const int col = blockIdx.y * 256 + tid;
  if (tid == 0) {
    unsigned f = 0;
    for (int i = 0; i < 64; ++i) f |= slots_s[i];
    fsh = f;
  }
  __syncthreads();
  const int smap_is_i32 = (fsh != 0);
  float a = 0.f;
  int cnt = 0;
  for (int i = 0; i < N; ++i) {
    const int s = smap_is_i32 ? ((const int*)smap)[i]
                              : (int)((const long long*)smap)[i];
    if (s == t) { a += pooled[(size_t)i * HDIM + col]; ++cnt; }
  }
  out[(size_t)t * HDIM + col] = a / (float)(cnt > 0 ? cnt : 1);
}

extern "C" void kernel_launch(void* const* d_in, const int* in_sizes, int n_in,
                              void* d_out, int out_size, void* d_ws, size_t ws_size,
                              hipStream_t stream) {
  const float*    hs     = (const float*)d_in[0];
  const unsigned* mask_w = (const unsigned*)d_in[1];
  const void*     smap   = d_in[2];
  const float*    Wq     = (const float*)d_in[3];
  const float*    bq     = (const float*)d_in[4];
  const float*    Wk     = (const float*)d_in[5];
  // d_in[6] = bk: dead (adds per-row constant to scores -> softmax-invariant)

  const int N = in_sizes[2];           // 512
  const int L = in_sizes[1] / N;       // 512
  const int H = in_sizes[4];           // 768 (== HDIM)
  const int T = out_size / H;          // 32

  float* Wc     = (float*)d_ws;                    // [H,H]
  float* c0     = Wc + (size_t)H * H;              // [H]
  float* pooled = c0 + H;                          // [N,H]
  unsigned* slots = (unsigned*)(pooled + (size_t)N * H);  // [128]
  (void)ws_size; (void)n_in;

  detect_slots<<<64, 256, 0, stream>>>(mask_w, (const unsigned*)smap, slots, N * L, N);
  prep_wc<<<dim3(H / 32, H / 64), 256, 0, stream>>>(Wq, Wk, bq, Wc, c0, H);
  fused<<<N, 384, 0, stream>>>(hs, mask_w, Wc, c0, slots, pooled, L);
  segmean<<<dim3(T, 3), 256, 0, stream>>>(pooled, smap, slots + 64, (float*)d_out, N);
}